// Round 7
// baseline (93.655 us; speedup 1.0000x reference)
//
#include <hip/hip_runtime.h>

// BilateralFilter3D 3x3x3, replicate pad, sigma_d=120, sigma_r=1.2
// (B,1,128,192,192) fp32.
//
// Round 13: after FOUR null scheduling levers (occupancy cap r10, DPP r10,
// prefetch depth-2 r11, 2x blocks r12) the surviving model is:
//   dispatch ~24us = launch/ramp (~8-10us) + compulsory stream ~65-75MB
//   (~14us) -- middle of the kernel already streams; only BYTES are left.
// Byte audit of v12: y-touch 1.5x (6 rows/plane for 4 outputs), z-touch
// 1.75x (7 planes/block for 4 outputs, ONE of them pure waste: the
// dz<ZC-1 guard loads z0+5 which no fold consumes), preambles 3072x4
// planes, and default round-robin XCD placement refetches shared boundary
// rows per-XCD. This round cuts touches ~32%, one coherent theory:
//  (1) 8-row blocks (512thr, 8 waves) x ZC=8 -> 768 blocks = exactly
//      3/CU uniform; y-touch 1.25x, z-touch 1.25x, preambles halved 2x.
//  (2) waste-plane guard fixed: dz < ZC-2 (folds end at dz=ZC-2, which
//      consumes plane z0+ZC, loaded at dz=ZC-3).
//  (3) XCD-contiguous bijective block swizzle (768%8==0): h/z-neighbor
//      blocks share an XCD L2 -> boundary re-reads hit L2 not LLC/HBM.
// Arithmetic untouched -> absmax must stay bit-identical 0.00390625.
// Predicted: dispatch ~20-21us, end-to-end ~84-86us. PRE-COMMIT: if null,
// bytes theory dies too; launch+stream floor stands -> ROOFLINE next.
//
// Math (unchanged from v9): w = B0 + B1*d^2 linear minimax on [0,1];
// separable box power sums S1,S2,S3:
//   den = 27B0 + B1*(S2 - 2c*S1 + 27c^2)
//   num = B0*S1 + B1*(S3 - 2c*S2 + c^2*S1), den >= ~18.9.

typedef float f3 __attribute__((ext_vector_type(3)));

constexpr int Dd = 128;
constexpr int Hh = 192;
constexpr int Ww = 192;
constexpr int ZC = 8;                 // z-steps per block
constexpr int RY = 8;                 // rows per block (8 waves)

constexpr int GX = Hh / RY;           // 24
constexpr int GY = Dd / ZC;           // 16

// linear minimax for exp(-t/(2*1.2^2)), t = d^2 in [0,1]; spatial weights
// (dev <= 1.05e-4 from 1) folded out entirely.
constexpr float B0 = 0.9936566f;
constexpr float B1 = -0.2933516f;

__device__ __forceinline__ f3 splat3(float v) { return (f3){v, v, v}; }
__device__ __forceinline__ f3 fma3(f3 a, f3 b, f3 c) {
    return __builtin_elementwise_fma(a, b, c);
}
__device__ __forceinline__ f3 fmas(f3 a, float b, f3 c) {
    return __builtin_elementwise_fma(a, splat3(b), c);
}

// lane i <- lane i-1 (wave_shr1); lane 0 keeps `oldv` (replicate clamp).
__device__ __forceinline__ float dpp_from_left(float oldv, float src) {
    int o = __builtin_bit_cast(int, oldv);
    int s = __builtin_bit_cast(int, src);
    int r = __builtin_amdgcn_update_dpp(o, s, 0x138, 0xF, 0xF, false);
    return __builtin_bit_cast(float, r);
}
// lane i <- lane i+1 (wave_shl1); lane 63 keeps `oldv` (replicate clamp).
__device__ __forceinline__ float dpp_from_right(float oldv, float src) {
    int o = __builtin_bit_cast(int, oldv);
    int s = __builtin_bit_cast(int, src);
    int r = __builtin_amdgcn_update_dpp(o, s, 0x130, 0xF, 0xF, false);
    return __builtin_bit_cast(float, r);
}

struct PS { f3 s1, s2, s3; };   // x-tapped, y-summed power sums

__global__ __launch_bounds__(512, 4)
void bilateral3d_v13(const float* __restrict__ vol, float* __restrict__ out)
{
    const int t  = threadIdx.x;              // lane 0..63 (== wave lane)
    const int ty = threadIdx.y;              // 0..7 (one wave per row)

    // XCD-contiguous bijective swizzle: hardware assigns original flat id
    // f to XCD f%8 (round-robin); block f does the WORK of id
    // (f%8)*(nwg/8) + f/8, so each XCD's blocks form a contiguous h x z
    // tile sharing boundary rows/planes in its private L2. nwg=768, %8==0.
    const int flat = blockIdx.x + GX * (blockIdx.y + GY * blockIdx.z);
    const int swz  = (flat & 7) * ((GX * GY * 2) >> 3) + (flat >> 3);
    const int bx   = swz % GX;
    const int rem  = swz / GX;
    const int by   = rem % GY;
    const int b    = rem / GY;

    const int h  = (bx << 3) + ty;           // 0..191
    const int z0 = by * ZC;                  // 0,8,...,120

    const size_t plane = (size_t)Hh * Ww;
    const float* __restrict__ base  = vol + (size_t)b * Dd * plane;
    float* __restrict__       obase = out + (size_t)b * Dd * plane;

    const int x0  = t * 3;                   // 3 voxels per lane, 64*3 = 192
    const int yy0 = (h > 0) ? h - 1 : 0;     // replicate via index clamp
    const int yy2 = (h < Hh - 1) ? h + 1 : Hh - 1;

    auto load_rows = [&](f3 dst[3], int z) {
        const float* __restrict__ zb = base + (size_t)z * plane + x0;
        const float* r0 = zb + (size_t)yy0 * Ww;
        const float* r1 = zb + (size_t)h   * Ww;
        const float* r2 = zb + (size_t)yy2 * Ww;
        dst[0] = (f3){r0[0], r0[1], r0[2]};
        dst[1] = (f3){r1[0], r1[1], r1[2]};
        dst[2] = (f3){r2[0], r2[1], r2[2]};
    };

    // x-tap with lane-crossing neighbors on a y-summed power row v.
    // u.x = v(x-1)+v(x)+v(x+1) etc.; boundary replicate handled by DPP `old`.
#define XTAP(vk, ok)                                                          \
    do {                                                                      \
        f3 v = (vk);                                                          \
        float L = dpp_from_left(v.x, v.z);                                    \
        float R = dpp_from_right(v.z, v.x);                                   \
        float t1 = v.x + v.y;                                                 \
        float t2 = v.y + v.z;                                                 \
        (ok) = (f3){L + t1, t1 + v.z, t2 + R};                                \
    } while (0)

    // raw 3 rows of one z-plane -> y+x collapsed power sums (3 f3)
    auto process = [&](const f3 r[3], PS& o) {
        f3 p2a = r[0] * r[0], p2b = r[1] * r[1], p2c = r[2] * r[2];
        f3 p3a = p2a * r[0], p3b = p2b * r[1], p3c = p2c * r[2];
        f3 v1 = r[0] + r[1] + r[2];
        f3 v2 = p2a + p2b + p2c;
        f3 v3 = p3a + p3b + p3c;
        XTAP(v1, o.s1);
        XTAP(v2, o.s2);
        XTAP(v3, o.s3);
    };

    PS P0, P1, P2;           // planes z-1, z, z+1
    f3 cenB, cenC;           // raw center rows of planes z, z+1
    f3 NR[3];                // raw rows of plane z+2 (in flight -> next step)
    {
        f3 Ra[3], Rb[3], Rc[3];
        load_rows(Ra, (z0 > 0) ? z0 - 1 : 0);
        load_rows(Rb, z0);
        load_rows(Rc, (z0 + 1 < Dd) ? z0 + 1 : Dd - 1);
        load_rows(NR, (z0 + 2 < Dd) ? z0 + 2 : Dd - 1);
        __builtin_amdgcn_sched_barrier(0);   // keep preamble loads batched
        process(Ra, P0);
        process(Rb, P1);
        process(Rc, P2);
        cenB = Rb[1];
        cenC = Rc[1];
    }

#pragma unroll
    for (int dz = 0; dz < ZC; ++dz) {
        const int z = z0 + dz;

        // issue loads for plane z+3 now; consumed at the END of the NEXT
        // step. Folds happen at end of steps 0..ZC-2 consuming planes
        // z0+2..z0+ZC, so the last useful load is at dz == ZC-3.
        f3 NN[3] = { splat3(0.f), splat3(0.f), splat3(0.f) };
        if (dz < ZC - 2) {
            load_rows(NN, (z + 3 < Dd) ? z + 3 : Dd - 1);
            __builtin_amdgcn_sched_barrier(0);
        }

        // ---- combine: z-sum the plane partials, Horner in c, write out ----
        f3 S1 = P0.s1 + P1.s1 + P2.s1;
        f3 S2 = P0.s2 + P1.s2 + P2.s2;
        f3 S3 = P0.s3 + P1.s3 + P2.s3;
        f3 c  = cenB;

        f3 m2S1 = splat3(-2.f) * S1;
        f3 m2S2 = splat3(-2.f) * S2;

        // M2 = S2 - 2c S1 + 27c^2 ; T2 = S3 - 2c S2 + c^2 S1
        f3 M2 = fma3(c, fmas(c, 27.f, m2S1), S2);
        f3 T2 = fma3(c, fma3(c, S1, m2S2), S3);

        f3 den = fmas(M2, B1, splat3(27.f * B0));
        f3 num = fmas(T2, B1, splat3(B0) * S1);

        // den >= ~18.9: reference clip(1e-8) is a no-op; fast rcp ~1ulp
        f3 r;
        r.x = num.x * __builtin_amdgcn_rcpf(den.x);
        r.y = num.y * __builtin_amdgcn_rcpf(den.y);
        r.z = num.z * __builtin_amdgcn_rcpf(den.z);

        float* __restrict__ orow = obase + (size_t)z * plane + (size_t)h * Ww + x0;
        orow[0] = r.x;
        orow[1] = r.y;
        orow[2] = r.z;

        // ---- fold plane z+2 into the window (skipped on the last step) ----
        if (dz < ZC - 1) {
            PS PN;
            process(NR, PN);        // waits on NR loads issued last iteration
            P0 = P1; P1 = P2; P2 = PN;
            cenB = cenC;
            cenC = NR[1];
            NR[0] = NN[0]; NR[1] = NN[1]; NR[2] = NN[2];
        }
    }
#undef XTAP
}

extern "C" void kernel_launch(void* const* d_in, const int* in_sizes, int n_in,
                              void* d_out, int out_size, void* d_ws, size_t ws_size,
                              hipStream_t stream)
{
    const float* vol = (const float*)d_in[0];
    float* out       = (float*)d_out;

    const int B = in_sizes[0] / (Dd * Hh * Ww);   // = 2

    dim3 grid(GX, GY, B);            // (24, 16, 2) = 768 blocks = 3/CU
    dim3 block(64, RY, 1);           // 512 threads = 8 waves, 1 wave per row
    bilateral3d_v13<<<grid, block, 0, stream>>>(vol, out);
}

// Round 8
// 92.003 us; speedup vs baseline: 1.0180x; 1.0180x over previous
//
#include <hip/hip_runtime.h>

// BilateralFilter3D 3x3x3, replicate pad, sigma_d=120, sigma_r=1.2
// (B,1,128,192,192) fp32.
//
// Round 14: REVERT to v10 (measured best: 88.535us end-to-end, dispatch
// ~23.6us). v13's -32%-bytes + XCD-swizzle + 8-wave blocks REGRESSED to
// 93.7us, falsifying the last live theory (bytes). Full lever ledger:
//   occupancy cap (r4) null | DPP (r4) null | prefetch depth-2 (r5) -2us |
//   2x block MLP (r6) null | bytes cut + swizzle (r7) -5us
// Surviving model: dispatch ~23.6us = launch/ramp (~8-10us, 1536-block
// short dispatch) + compulsory ~65-75MB HBM stream (~14us; harness fill
// evicts input from LLC each iter). VALU issue floor ~5us is fully hidden.
// No remaining lever attacks launch overhead or compulsory fp32 bytes ->
// this is the structural floor; expect ROOFLINE verdict if reproduced.
//
// Math (from v9): w = B0 + B1*d^2 linear minimax on [0,1] (|err|<=0.00634),
// spatial weights folded out; separable box power sums S1,S2,S3:
//   den = 27B0 + B1*(S2 - 2c*S1 + 27c^2)
//   num = B0*S1 + B1*(S3 - 2c*S2 + c^2*S1), den >= ~18.9 -> fast rcp safe.
// Structure: 64 lanes x 3 voxels = one 192-row per wave; x-neighbors via
// DPP wave_shr1/shl1 (old = clamped edge -> replicate for free); rotating
// 3-plane window of (s1,s2,s3) partials; depth-1 plane prefetch; ZC=8.

typedef float f3 __attribute__((ext_vector_type(3)));

constexpr int Dd = 128;
constexpr int Hh = 192;
constexpr int Ww = 192;
constexpr int ZC = 8;                 // z-steps per block

// linear minimax for exp(-t/(2*1.2^2)), t = d^2 in [0,1]
constexpr float B0 = 0.9936566f;
constexpr float B1 = -0.2933516f;

__device__ __forceinline__ f3 splat3(float v) { return (f3){v, v, v}; }
__device__ __forceinline__ f3 fma3(f3 a, f3 b, f3 c) {
    return __builtin_elementwise_fma(a, b, c);
}
__device__ __forceinline__ f3 fmas(f3 a, float b, f3 c) {
    return __builtin_elementwise_fma(a, splat3(b), c);
}

// lane i <- lane i-1 (wave_shr1); lane 0 keeps `oldv` (replicate clamp).
__device__ __forceinline__ float dpp_from_left(float oldv, float src) {
    int o = __builtin_bit_cast(int, oldv);
    int s = __builtin_bit_cast(int, src);
    int r = __builtin_amdgcn_update_dpp(o, s, 0x138, 0xF, 0xF, false);
    return __builtin_bit_cast(float, r);
}
// lane i <- lane i+1 (wave_shl1); lane 63 keeps `oldv` (replicate clamp).
__device__ __forceinline__ float dpp_from_right(float oldv, float src) {
    int o = __builtin_bit_cast(int, oldv);
    int s = __builtin_bit_cast(int, src);
    int r = __builtin_amdgcn_update_dpp(o, s, 0x130, 0xF, 0xF, false);
    return __builtin_bit_cast(float, r);
}

struct PS { f3 s1, s2, s3; };   // x-tapped, y-summed power sums

__global__ __launch_bounds__(256, 4)
void bilateral3d_v14(const float* __restrict__ vol, float* __restrict__ out)
{
    const int t  = threadIdx.x;              // lane 0..63 (== wave lane)
    const int ty = threadIdx.y;              // 0..3
    const int h  = (blockIdx.x << 2) + ty;   // 0..191
    const int z0 = blockIdx.y * ZC;          // 0,8,...,120
    const int b  = blockIdx.z;

    const size_t plane = (size_t)Hh * Ww;
    const float* __restrict__ base  = vol + (size_t)b * Dd * plane;
    float* __restrict__       obase = out + (size_t)b * Dd * plane;

    const int x0  = t * 3;                   // 3 voxels per lane, 64*3 = 192
    const int yy0 = (h > 0) ? h - 1 : 0;     // replicate via index clamp
    const int yy2 = (h < Hh - 1) ? h + 1 : Hh - 1;

    auto load_rows = [&](f3 dst[3], int z) {
        const float* __restrict__ zb = base + (size_t)z * plane + x0;
        const float* r0 = zb + (size_t)yy0 * Ww;
        const float* r1 = zb + (size_t)h   * Ww;
        const float* r2 = zb + (size_t)yy2 * Ww;
        dst[0] = (f3){r0[0], r0[1], r0[2]};
        dst[1] = (f3){r1[0], r1[1], r1[2]};
        dst[2] = (f3){r2[0], r2[1], r2[2]};
    };

    // x-tap with lane-crossing neighbors on a y-summed power row v.
    // u.x = v(x-1)+v(x)+v(x+1) etc.; boundary replicate handled by DPP `old`.
#define XTAP(vk, ok)                                                          \
    do {                                                                      \
        f3 v = (vk);                                                          \
        float L = dpp_from_left(v.x, v.z);                                    \
        float R = dpp_from_right(v.z, v.x);                                   \
        float t1 = v.x + v.y;                                                 \
        float t2 = v.y + v.z;                                                 \
        (ok) = (f3){L + t1, t1 + v.z, t2 + R};                                \
    } while (0)

    // raw 3 rows of one z-plane -> y+x collapsed power sums (3 f3)
    auto process = [&](const f3 r[3], PS& o) {
        f3 p2a = r[0] * r[0], p2b = r[1] * r[1], p2c = r[2] * r[2];
        f3 p3a = p2a * r[0], p3b = p2b * r[1], p3c = p2c * r[2];
        f3 v1 = r[0] + r[1] + r[2];
        f3 v2 = p2a + p2b + p2c;
        f3 v3 = p3a + p3b + p3c;
        XTAP(v1, o.s1);
        XTAP(v2, o.s2);
        XTAP(v3, o.s3);
    };

    PS P0, P1, P2;           // planes z-1, z, z+1
    f3 cenB, cenC;           // raw center rows of planes z, z+1
    f3 NR[3];                // raw rows of plane z+2 (in flight -> next step)
    {
        f3 Ra[3], Rb[3], Rc[3];
        load_rows(Ra, (z0 > 0) ? z0 - 1 : 0);
        load_rows(Rb, z0);
        load_rows(Rc, (z0 + 1 < Dd) ? z0 + 1 : Dd - 1);
        load_rows(NR, (z0 + 2 < Dd) ? z0 + 2 : Dd - 1);
        __builtin_amdgcn_sched_barrier(0);   // keep preamble loads batched
        process(Ra, P0);
        process(Rb, P1);
        process(Rc, P2);
        cenB = Rb[1];
        cenC = Rc[1];
    }

#pragma unroll
    for (int dz = 0; dz < ZC; ++dz) {
        const int z = z0 + dz;

        // issue loads for plane z+3 now; consumed NEXT iteration.
        f3 NN[3] = { splat3(0.f), splat3(0.f), splat3(0.f) };
        if (dz < ZC - 1) {
            load_rows(NN, (z + 3 < Dd) ? z + 3 : Dd - 1);
            __builtin_amdgcn_sched_barrier(0);
        }

        // ---- combine: z-sum the plane partials, Horner in c, write out ----
        f3 S1 = P0.s1 + P1.s1 + P2.s1;
        f3 S2 = P0.s2 + P1.s2 + P2.s2;
        f3 S3 = P0.s3 + P1.s3 + P2.s3;
        f3 c  = cenB;

        f3 m2S1 = splat3(-2.f) * S1;
        f3 m2S2 = splat3(-2.f) * S2;

        // M2 = S2 - 2c S1 + 27c^2 ; T2 = S3 - 2c S2 + c^2 S1
        f3 M2 = fma3(c, fmas(c, 27.f, m2S1), S2);
        f3 T2 = fma3(c, fma3(c, S1, m2S2), S3);

        f3 den = fmas(M2, B1, splat3(27.f * B0));
        f3 num = fmas(T2, B1, splat3(B0) * S1);

        // den >= ~18.9: reference clip(1e-8) is a no-op; fast rcp ~1ulp
        f3 r;
        r.x = num.x * __builtin_amdgcn_rcpf(den.x);
        r.y = num.y * __builtin_amdgcn_rcpf(den.y);
        r.z = num.z * __builtin_amdgcn_rcpf(den.z);

        float* __restrict__ orow = obase + (size_t)z * plane + (size_t)h * Ww + x0;
        orow[0] = r.x;
        orow[1] = r.y;
        orow[2] = r.z;

        // ---- fold plane z+2 into the window (skipped on the last step) ----
        if (dz < ZC - 1) {
            PS PN;
            process(NR, PN);        // waits on NR loads issued last iteration
            P0 = P1; P1 = P2; P2 = PN;
            cenB = cenC;
            cenC = NR[1];
            NR[0] = NN[0]; NR[1] = NN[1]; NR[2] = NN[2];
        }
    }
#undef XTAP
}

extern "C" void kernel_launch(void* const* d_in, const int* in_sizes, int n_in,
                              void* d_out, int out_size, void* d_ws, size_t ws_size,
                              hipStream_t stream)
{
    const float* vol = (const float*)d_in[0];
    float* out       = (float*)d_out;

    const int B = in_sizes[0] / (Dd * Hh * Ww);   // = 2

    dim3 grid(Hh / 4, Dd / ZC, B);   // (48, 16, 2) = 1536 blocks
    dim3 block(64, 4, 1);            // 256 threads = 4 waves, 1 wave per row
    bilateral3d_v14<<<grid, block, 0, stream>>>(vol, out);
}